// Round 12
// baseline (3523.919 us; speedup 1.0000x reference)
//
#include <hip/hip_runtime.h>

// ---------------------------------------------------------------------------
// TRecTransformer on MI355X. Round 12: fix the 8-way LDS read conflict that
// round 11's coalesced [128][32] layout introduced (4.2M conflicts/dispatch).
// T2 XOR swizzle via pre-swizzled GLOBAL source (global_load_lds dest must
// stay linear, rule #21): slot s loads (row=s>>2, kc=(s&3)^((s>>3)&3));
// fragment (r,kg) reads slot r*4 + (kg^((r>>1)&3)). 4-lane groups still
// cover one 64B line (coalescing kept); read spreads all 8 granule-groups
// (2-way = free). Everything else identical to round 11.
// ---------------------------------------------------------------------------

#define NB 4
#define NSEQ 4096
#define NH 8
#define DQ 64
#define DM 512
#define DFF 2048
#define MROWS (NB * NSEQ)          // 16384
#define SZ ((long)MROWS * DM)      // 8388608 elems

typedef unsigned short u16;
typedef unsigned int u32;
typedef __bf16 bfv8 __attribute__((ext_vector_type(8)));
typedef float f32x4 __attribute__((ext_vector_type(4)));

__device__ __forceinline__ float bf2f(u16 u) {
  union { unsigned u; float f; } v; v.u = ((unsigned)u) << 16; return v.f;
}
__device__ __forceinline__ u16 f2bf(float f) {
  union { float f; unsigned u; } v; v.f = f;
  unsigned r = v.u + 0x7FFFu + ((v.u >> 16) & 1u);
  return (u16)(r >> 16);
}
__device__ __forceinline__ float ldin(const void* p, long i, int bf) {
  return bf ? bf2f(((const u16*)p)[i]) : ((const float*)p)[i];
}
// split store for the residual stream: h+l reproduces fp32 to ~2^-18 rel.
__device__ __forceinline__ void st2(float v, u16* __restrict__ h,
                                    u16* __restrict__ l, long off) {
  u16 hh = f2bf(v);
  h[off] = hh;
  l[off] = f2bf(v - bf2f(hh));
}
__device__ __forceinline__ float ld2(const u16* __restrict__ h,
                                     const u16* __restrict__ l, long off) {
  return bf2f(h[off]) + bf2f(l[off]);
}
// async global->LDS, 16B per lane. lds base must be wave-uniform; HW writes
// lane i's 16B at base + i*16.
__device__ __forceinline__ void gld16(const u16* g, u16* l) {
  __builtin_amdgcn_global_load_lds(
      (const __attribute__((address_space(1))) unsigned int*)g,
      (__attribute__((address_space(3))) unsigned int*)l, 16, 0, 0);
}

// --- dtype probe -----------------------------------------------------------
__global__ void detect_k(const unsigned* __restrict__ lnp, int* __restrict__ flag) {
  if (threadIdx.x == 0 && blockIdx.x == 0)
    *flag = (lnp[0] == 0x3F803F80u) ? 1 : 0;
}

// --- weight transpose: W[K][N] (input dtype) -> dst[N][K] bf16, batched -----
__global__ __launch_bounds__(256) void wtr_k(
    const void* __restrict__ W, long srcstride, int K, int N,
    u16* __restrict__ dst, long dststride, const int* __restrict__ flag) {
  int bf = *flag;
  __shared__ u16 tile[64][65];
  long mb = blockIdx.z;
  int n0 = blockIdx.x * 64, k0 = blockIdx.y * 64;
  int t = threadIdx.x;
  int r = t >> 2, c0 = (t & 3) << 4;
  long sb = mb * srcstride;
#pragma unroll
  for (int c = 0; c < 16; c++)
    tile[r][c0 + c] = f2bf(ldin(W, sb + (long)(k0 + r) * N + n0 + c0 + c, bf));
  __syncthreads();
  long db = mb * dststride;
#pragma unroll
  for (int c = 0; c < 16; c++)
    dst[db + (long)(n0 + r) * K + k0 + c0 + c] = tile[c0 + c][r];
}

// --- embed: row = concat(x[b,n,0:2], pe[n,0:510]) -> split stream ----------
__global__ __launch_bounds__(256) void embed_k(
    const void* __restrict__ xin, const void* __restrict__ pe,
    u16* __restrict__ Hh, u16* __restrict__ Hl,
    const int* __restrict__ flag) {
  int bf = *flag;
  long idx = (long)blockIdx.x * 256 + threadIdx.x;   // < MROWS*DM
  long row = idx >> 9;
  int  c   = (int)(idx & 511);
  long n   = row & (NSEQ - 1);
  float v = (c < 2) ? ldin(xin, row * 2 + c, bf)
                    : ldin(pe, n * 510 + (c - 2), bf);
  st2(v, Hh, Hl, idx);
}

// --- MFMA GEMM: C[M,N] = act(A @ Bt^T + bias) ------------------------------
// A: one bf16 plane, lda stride. 4-buffer depth-3 counted-vmcnt pipeline.
// Swizzled-coalesced staging (rule #21): slot s loads global
// (row = s>>2, kc = (s&3)^((s>>3)&3)); DMA writes slot s linearly.
// Fragment (r,kg) reads slot r*4 + (kg ^ ((r>>1)&3)) -> all 8 LDS
// granule-groups hit per 8 lanes (2-way = free). 4-lane groups still load
// one contiguous 64B line (global coalescing kept).
// Out: Ch u16 via wave-private LDS-staged coalesced uint2 stores, or Cf
// fp32 direct (accum optional). act = (cc < actT) ? act0 : act1.
// Tile 128x128, BK=32, 4 waves, XCD-bijective swizzle (nwg % 8 == 0).
// Dynamic LDS: 4 bufs x 2 tensors x 4096 u16 = 64 KB.
__global__ __launch_bounds__(256) void mm_k(
    const u16* __restrict__ A, long lda,
    const u16* __restrict__ Bt, long ldb, int K,
    const void* __restrict__ bias, long boff, int hasb,
    u16* __restrict__ Ch, float* __restrict__ Cf, int accum, long ldc,
    int actT, int act0, int act1, int nbx, const int* __restrict__ flag) {
  extern __shared__ __align__(16) u16 S[];         // [4][2][4096]
  const int t = threadIdx.x;
  const int nwg = gridDim.x;
  const int cpx = nwg >> 3;
  const int swz = (blockIdx.x & 7) * cpx + (blockIdx.x >> 3);
  const long row0 = (long)(swz / nbx) * 128;
  const long col0 = (long)(swz % nbx) * 128;
  // swizzled-coalesced slot map: slot s -> row = s>>2, kc = (s&3)^((s>>3)&3)
  const int s0 = t, s1 = t + 256;
  const int r0 = s0 >> 2, kc0 = (s0 & 3) ^ ((s0 >> 3) & 3);
  const int r1 = s1 >> 2, kc1 = (s1 & 3) ^ ((s1 >> 3) & 3);
  const u16* pA0 = A + (row0 + r0) * lda + 8 * kc0;
  const u16* pA1 = A + (row0 + r1) * lda + 8 * kc1;
  const u16* pB0 = Bt + (col0 + r0) * ldb + 8 * kc0;
  const u16* pB1 = Bt + (col0 + r1) * ldb + 8 * kc1;
  const int lane = t & 63, w = t >> 6;
  // wave-uniform LDS slot bases (slot 64w and 64w+256), 8 u16/slot
  const long wb0 = (long)(w * 64) * 8;
  const long wb1 = (long)(w * 64 + 256) * 8;
  const int kg = lane >> 4, q = lane & 15;
  const int xq = (q >> 1) & 3;           // read-side swizzle key
  const int kgx = (kg ^ xq) * 8;         // swizzled k-chunk offset (u16)
  const int wm = (w >> 1) * 64, wn = (w & 1) * 64;
  f32x4 acc[4][4] = {};

  auto tbase = [&](int b, int tns) -> u16* { return S + (((b << 1) + tns) << 12); };
  auto issue = [&](int b, int k) {
    u16* bA = tbase(b, 0);
    u16* bB = tbase(b, 1);
    gld16(pA0 + k, bA + wb0); gld16(pA1 + k, bA + wb1);
    gld16(pB0 + k, bB + wb0); gld16(pB1 + k, bB + wb1);
  };
  auto compute = [&](int b) {
    const u16* sA = tbase(b, 0);
    const u16* sB = tbase(b, 1);
    bfv8 fa[4];
#pragma unroll
    for (int i = 0; i < 4; i++)
      fa[i] = *(const bfv8*)(sA + (long)(wm + i * 16 + q) * 32 + kgx);
    __builtin_amdgcn_s_setprio(1);
#pragma unroll
    for (int j = 0; j < 4; j++) {
      bfv8 fb = *(const bfv8*)(sB + (long)(wn + j * 16 + q) * 32 + kgx);
#pragma unroll
      for (int i = 0; i < 4; i++)
        acc[i][j] = __builtin_amdgcn_mfma_f32_16x16x32_bf16(fa[i], fb, acc[i][j], 0, 0, 0);
    }
    __builtin_amdgcn_s_setprio(0);
  };

  const int nt = K >> 5;                  // 16 / 64 K-steps (>= 16)
  issue(0, 0);
  issue(1, 32);
  issue(2, 64);
  for (int i = 0; i < nt - 2; ++i) {      // steady state: lookahead 3
    asm volatile("s_waitcnt vmcnt(8)" ::: "memory");   // tile i landed
    __builtin_amdgcn_s_barrier();
    __builtin_amdgcn_sched_barrier(0);
    if (i + 3 < nt) issue((i + 3) & 3, (i + 3) * 32);  // buf freed at barrier
    compute(i & 3);
  }
  // tail peel: outstanding shrinks -> counted waits must shrink too
  asm volatile("s_waitcnt vmcnt(4)" ::: "memory");     // tile nt-2 landed
  __builtin_amdgcn_s_barrier();
  __builtin_amdgcn_sched_barrier(0);
  compute((nt - 2) & 3);
  asm volatile("s_waitcnt vmcnt(0)" ::: "memory");     // tile nt-1 landed
  __builtin_amdgcn_s_barrier();
  __builtin_amdgcn_sched_barrier(0);
  compute((nt - 1) & 3);

  __syncthreads();                       // all reads of S done; reuse as ws
  const int bf = *flag;
  if (Ch) {
    // Wave-private staged epilogue: u16 quadrant [64][stride 68], then
    // coalesced uint2 stores (each 16-lane group covers a 128B row run).
    u16* ws = S + (long)w * 4352;        // 64*68 u16 = 8704 B/wave
#pragma unroll
    for (int j = 0; j < 4; j++) {
      const long cc = col0 + wn + j * 16 + q;
      const int act = (cc < actT) ? act0 : act1;
      const float bv = hasb ? ldin(bias, boff + cc, bf) : 0.f;
#pragma unroll
      for (int i = 0; i < 4; i++)
#pragma unroll
        for (int r = 0; r < 4; r++) {
          float v = acc[i][j][r] + bv;
          if (act == 1) v = (v > 0.f) ? v + 1.f : __expf(v);
          else if (act == 2) v = fmaxf(v, 0.f);
          ws[(i * 16 + kg * 4 + r) * 68 + j * 16 + q] = f2bf(v);
        }
    }
    asm volatile("s_waitcnt lgkmcnt(0)" ::: "memory"); // wave ws writes done
    __builtin_amdgcn_sched_barrier(0);
#pragma unroll
    for (int m = 0; m < 16; m++) {
      const int slot = m * 64 + lane;
      const int row = slot >> 4, seg = slot & 15;
      uint2 c2 = *(const uint2*)&ws[row * 68 + seg * 4];
      const long off = (row0 + wm + row) * ldc + col0 + wn + seg * 4;
      *(uint2*)&Ch[off] = c2;
    }
  } else {
#pragma unroll
    for (int j = 0; j < 4; j++) {
      const long cc = col0 + wn + j * 16 + q;
      const int act = (cc < actT) ? act0 : act1;
      const float bv = hasb ? ldin(bias, boff + cc, bf) : 0.f;
#pragma unroll
      for (int i = 0; i < 4; i++) {
        const long rb = row0 + wm + i * 16 + kg * 4;
#pragma unroll
        for (int r = 0; r < 4; r++) {
          float v = acc[i][j][r] + bv;
          if (act == 1) v = (v > 0.f) ? v + 1.f : __expf(v);
          else if (act == 2) v = fmaxf(v, 0.f);
          const long off = (rb + r) * ldc + cc;
          Cf[off] = accum ? Cf[off] + v : v;
        }
      }
    }
  }
}

// --- kv partial: per (b,h,chunk): kv_part[64][64] += k_n ⊗ v_n over 512 rows
// K at S cols [512,1024), V at [1024,1536), row stride 1536, single plane.
__global__ __launch_bounds__(256) void kv_partial_k(
    const u16* __restrict__ Sh,
    float* __restrict__ kvp, float* __restrict__ ksp) {
  int bh = blockIdx.x;           // 0..31
  int b = bh >> 3, h = bh & 7;
  int nc = blockIdx.y;           // 0..7
  int tid = threadIdx.x;
  __shared__ float Ks[8][64], Vs[8][64];
  float acc[16] = {};
  float ks = 0.f;
  int d  = tid >> 2;             // 0..63
  int e0 = (tid & 3) << 4;       // 0,16,32,48
  int lr = tid >> 5;             // 0..7
  int lc = (tid & 31) << 1;      // 0..62
  long base = ((long)b * NSEQ + (long)nc * 512) * 1536 + 512 + h * DQ;
  for (int n8 = 0; n8 < 64; n8++) {
    long gg = base + (long)(n8 * 8 + lr) * 1536 + lc;
    u32 k2 = *(const u32*)(Sh + gg);
    u32 v2 = *(const u32*)(Sh + gg + 512);
    __syncthreads();
    Ks[lr][lc]     = bf2f((u16)k2);
    Ks[lr][lc + 1] = bf2f((u16)(k2 >> 16));
    Vs[lr][lc]     = bf2f((u16)v2);
    Vs[lr][lc + 1] = bf2f((u16)(v2 >> 16));
    __syncthreads();
#pragma unroll
    for (int r2 = 0; r2 < 8; r2++) {
      float kd = Ks[r2][d];
#pragma unroll
      for (int m = 0; m < 16; m++) acc[m] += kd * Vs[r2][e0 + m];
    }
    if (tid < 64) {
#pragma unroll
      for (int r2 = 0; r2 < 8; r2++) ks += Ks[r2][tid];
    }
  }
  long ob = ((long)bh * 8 + nc) * 4096 + (long)d * 64 + e0;
#pragma unroll
  for (int m = 0; m < 16; m++) kvp[ob + m] = acc[m];
  if (tid < 64) ksp[((long)bh * 8 + nc) * 64 + tid] = ks;
}

// --- kv reduce: sum the 8 chunks ------------------------------------------
__global__ __launch_bounds__(256) void kv_reduce_k(
    const float* __restrict__ kvp, const float* __restrict__ ksp,
    float* __restrict__ kv, float* __restrict__ ksum) {
  int bh = blockIdx.x;
  int tid = threadIdx.x;
  for (int i = tid; i < 4096; i += 256) {
    float s = 0.f;
#pragma unroll
    for (int c = 0; c < 8; c++) s += kvp[((long)bh * 8 + c) * 4096 + i];
    kv[(long)bh * 4096 + i] = s;
  }
  if (tid < 64) {
    float s = 0.f;
#pragma unroll
    for (int c = 0; c < 8; c++) s += ksp[((long)bh * 8 + c) * 64 + tid];
    ksum[(long)bh * 64 + tid] = s;
  }
}

// --- o = (q @ kv) / (q·ksum + eps); Q from S cols [0,512), O in place ------
__global__ __launch_bounds__(256) void attn_o_k(
    u16* __restrict__ Sh,
    const float* __restrict__ kv, const float* __restrict__ ksum) {
  int bh = blockIdx.x;
  int b = bh >> 3, h = bh & 7;
  int n0 = blockIdx.y * 64;
  int tid = threadIdx.x;
  __shared__ float Qs[64][65];
  __shared__ float KVs[64][64];
  __shared__ float ks_s[64];
  __shared__ float dinv[64];
  for (int i = tid; i < 4096; i += 256) {
    KVs[i >> 6][i & 63] = kv[(long)bh * 4096 + i];
    long qi = ((long)b * NSEQ + n0 + (i >> 6)) * 1536 + h * DQ + (i & 63);
    Qs[i >> 6][i & 63] = bf2f(Sh[qi]);
  }
  if (tid < 64) ks_s[tid] = ksum[(long)bh * 64 + tid];
  __syncthreads();
  if (tid < 64) {
    float s = 0.f;
#pragma unroll
    for (int dd = 0; dd < 64; dd++) s += Qs[tid][dd] * ks_s[dd];
    dinv[tid] = 1.f / (s + 1e-6f);
  }
  __syncthreads();
  int tx = tid & 15, ty = tid >> 4;
  float acc[4][4] = {};
#pragma unroll 4
  for (int dd = 0; dd < 64; dd++) {
    float a[4];
#pragma unroll
    for (int i = 0; i < 4; i++) a[i] = Qs[(ty << 2) + i][dd];
    float4 b4 = *(const float4*)&KVs[dd][tx << 2];
    float bb[4] = {b4.x, b4.y, b4.z, b4.w};
#pragma unroll
    for (int i = 0; i < 4; i++)
#pragma unroll
      for (int j = 0; j < 4; j++) acc[i][j] += a[i] * bb[j];
  }
#pragma unroll
  for (int i = 0; i < 4; i++) {
    float z = dinv[(ty << 2) + i];
    long ro = ((long)b * NSEQ + n0 + (ty << 2) + i) * 1536 + h * DQ + (tx << 2);
#pragma unroll
    for (int j = 0; j < 4; j++) Sh[ro + j] = f2bf(acc[i][j] * z);
  }
}

// --- Out = LN(Xh+Xl (+Yf)) * scale + bias, split stream out ----------------
__global__ __launch_bounds__(256) void add_ln_k(
    const u16* __restrict__ Xh, const u16* __restrict__ Xl,
    const float* __restrict__ Yf,
    const void* __restrict__ lnp, long lnoff,
    u16* __restrict__ Oh, u16* __restrict__ Ol,
    const int* __restrict__ flag) {
  int bf = *flag;
  long r = blockIdx.x;
  int tid = threadIdx.x;
  long base = r * DM;
  float x0 = ld2(Xh, Xl, base + tid);
  float x1 = ld2(Xh, Xl, base + tid + 256);
  if (Yf) { x0 += Yf[base + tid]; x1 += Yf[base + tid + 256]; }
  float s = x0 + x1, sq = x0 * x0 + x1 * x1;
  for (int off = 32; off; off >>= 1) {
    s  += __shfl_down(s, off, 64);
    sq += __shfl_down(sq, off, 64);
  }
  __shared__ float red[8];
  __shared__ float mv[2];
  int w = tid >> 6;
  if ((tid & 63) == 0) { red[w] = s; red[4 + w] = sq; }
  __syncthreads();
  if (tid == 0) {
    float S = red[0] + red[1] + red[2] + red[3];
    float Q2 = red[4] + red[5] + red[6] + red[7];
    float m = S * (1.f / 512.f);
    float v = Q2 * (1.f / 512.f) - m * m;
    mv[0] = m; mv[1] = rsqrtf(v + 1e-5f);
  }
  __syncthreads();
  float m = mv[0], rs = mv[1];
  float y0 = (x0 - m) * rs * ldin(lnp, lnoff + tid, bf) + ldin(lnp, lnoff + 512 + tid, bf);
  float y1 = (x1 - m) * rs * ldin(lnp, lnoff + 256 + tid, bf) + ldin(lnp, lnoff + 768 + tid, bf);
  st2(y0, Oh, Ol, base + tid);
  st2(y1, Oh, Ol, base + tid + 256);
}

// --- heads: out[r,0]=t·ampW+ab, out[r,1]=tanh(t·phW+pb) --------------------
__global__ __launch_bounds__(256) void heads_k(
    const u16* __restrict__ Th, const u16* __restrict__ Tl,
    const void* __restrict__ aW, const void* __restrict__ pW,
    const void* __restrict__ ab, const void* __restrict__ pb,
    void* __restrict__ out, const int* __restrict__ flag) {
  int bf = *flag;
  int tid = threadIdx.x, w = tid >> 6, ln = tid & 63;
  long r = (long)blockIdx.x * 4 + w;
  float sa = 0.f, sp = 0.f;
#pragma unroll
  for (int i = 0; i < 8; i++) {
    int d = ln + i * 64;
    float xv = ld2(Th, Tl, r * DM + d);
    sa += xv * ldin(aW, d, bf);
    sp += xv * ldin(pW, d, bf);
  }
  for (int off = 32; off; off >>= 1) {
    sa += __shfl_down(sa, off, 64);
    sp += __shfl_down(sp, off, 64);
  }
  if (ln == 0) {
    float amp = sa + ldin(ab, 0, bf);
    float ph  = tanhf(sp + ldin(pb, 0, bf));
    if (bf) {
      ((u16*)out)[r * 2]     = f2bf(amp);
      ((u16*)out)[r * 2 + 1] = f2bf(ph);
    } else {
      ((float*)out)[r * 2]     = amp;
      ((float*)out)[r * 2 + 1] = ph;
    }
  }
}

// ---------------------------------------------------------------------------
extern "C" void kernel_launch(void* const* d_in, const int* in_sizes, int n_in,
                              void* d_out, int out_size, void* d_ws, size_t ws_size,
                              hipStream_t stream) {
  const void* x       = d_in[0];
  const void* tfc     = d_in[1];
  const void* pe_s    = d_in[2];
  const void* pe_t    = d_in[3];
  const void* enc_W   = d_in[4];
  const void* enc_b   = d_in[5];
  const void* enc_ln  = d_in[6];
  const void* enc_fW1 = d_in[7];
  const void* enc_fb1 = d_in[8];
  const void* enc_fW2 = d_in[9];
  const void* enc_fb2 = d_in[10];
  const void* enc_fln = d_in[11];
  const void* dec_W   = d_in[12];
  const void* dec_b   = d_in[13];
  const void* dec_ln  = d_in[14];
  const void* dec_fW1 = d_in[15];
  const void* dec_fb1 = d_in[16];
  const void* dec_fW2 = d_in[17];
  const void* dec_fb2 = d_in[18];
  const void* dec_fln = d_in[19];
  const void* amp_W   = d_in[20];
  const void* amp_b   = d_in[21];
  const void* ph_W    = d_in[22];
  const void* ph_b    = d_in[23];

  // ws layout, u16 units (extents proven rounds 2-11):
  //   [0,2SZ)   : Hh | Hl  residual stream, split (32 MiB)
  //   [2SZ,4SZ) : Mh | Ml  memory, split (32 MiB)
  //   [4SZ,10SZ): scratch union
  //       attn: S = [16384][1536] u16 single plane at [4SZ,7SZ)
  //       ffn : Fc = [16384][2048] u16 at [4SZ,8SZ)
  //       both: Yf fp32 [8SZ,10SZ)
  //   [10SZ,12SZ): weight arena (32 MiB), enc staged then dec overwrites
  //   [12SZ,...) : fp32 smalls kv | ksum | ksp | kvp | flag (~4.8 MiB)
  u16* U  = (u16*)d_ws;
  u16* Hh = U;            u16* Hl = U + SZ;
  u16* Mh = U + 2 * SZ;   u16* Ml = U + 3 * SZ;
  u16* Sh = U + 4 * SZ;
  u16* Fch = U + 4 * SZ;
  float* Yf = (float*)(U + 8 * SZ);
  u16* WtQ = U + 10 * SZ;            // qkvo: enc 16xW4 / dec 32xW4
  u16* Wt1 = WtQ + 8388608;          // fW1^T: 4xFFW
  u16* Wt2 = WtQ + 12582912;         // fW2^T: 4xFFW
  float* F = (float*)(U + 12 * SZ);
  float* kvb   = F;                   // 32*4096
  float* ksumb = kvb + 32 * 4096;     // 2048
  float* ksp   = ksumb + 2048;        // 32*8*64
  float* kvp   = ksp + 32 * 8 * 64;   // 32*8*4096
  int*   flag  = (int*)(kvp + 32 * 8 * 4096);

  const long W4  = (long)DM * DM;    // 262144
  const long FFW = (long)DM * DFF;   // 1048576
  const size_t MMLDS = 4 * 2 * 4096 * sizeof(u16);   // 64 KB

  auto mm = [&](const u16* a, long lda, const u16* bt, long ldb, int K,
                const void* bias, long boff, int hasb,
                u16* ch, float* cf, int accum, long ldc,
                int actT, int act0, int act1, int N) {
    int nbx = N / 128;
    mm_k<<<dim3(nbx * (MROWS / 128)), dim3(256), MMLDS, stream>>>(
        a, lda, bt, ldb, K, bias, boff, hasb, ch, cf, accum, ldc,
        actT, act0, act1, nbx, flag);
  };
  auto addln = [&](const u16* xh, const u16* xl, const float* yf,
                   const void* lnp, long lnoff, u16* oh, u16* ol) {
    add_ln_k<<<dim3(MROWS), dim3(256), 0, stream>>>(
        xh, xl, yf, lnp, lnoff, oh, ol, flag);
  };
  auto attn_core = [&](const u16* Wq, const void* bb, long b0) {
    kv_partial_k<<<dim3(32, 8), dim3(256), 0, stream>>>(Sh, kvp, ksp);
    kv_reduce_k<<<dim3(32), dim3(256), 0, stream>>>(kvp, ksp, kvb, ksumb);
    attn_o_k<<<dim3(32, 64), dim3(256), 0, stream>>>(Sh, kvb, ksumb);
    // o-proj: A = O (S cols 0..511), out -> fp32 Yf (precision hedge)
    mm(Sh, 1536, Wq + 3 * W4, DM, DM, bb, b0 + 3 * DM, 1,
       nullptr, Yf, 0, DM, 512, 0, 0, DM);
  };
  auto attn_self = [&](const u16* Wq, const void* bb, long b0) {
    // fused QKV: N=1536, elu on Q,K (cc<1024), none on V
    mm(Hh, DM, Wq, DM, DM, bb, b0, 1, Sh, nullptr, 0, 1536,
       1024, 1, 0, 1536);
    attn_core(Wq, bb, b0);
  };
  auto attn_cross = [&](const u16* Wq, const void* bb, long b0) {
    mm(Hh, DM, Wq, DM, DM, bb, b0, 1, Sh, nullptr, 0, 1536,
       512, 1, 0, DM);                                              // Q
    mm(Mh, DM, Wq + W4, DM, DM, bb, b0 + DM, 1,
       Sh + 512, nullptr, 0, 1536, 512, 1, 0, 1024);                // K|V
    attn_core(Wq, bb, b0);
  };
  auto ffn = [&](const u16* w1t, const void* b1, long b1o,
                 const u16* w2t, const void* b2, long b2o) {
    // full-width: FFN1 N=2048 (relu), FFN2 K=2048 single pass -> Yf
    mm(Hh, DM, w1t, DM, DM, b1, b1o, 1, Fch, nullptr, 0, DFF, 0, 2, 2, DFF);
    mm(Fch, DFF, w2t, DFF, DFF, b2, b2o, 1, nullptr, Yf, 0, DM, 0, 0, 0, DM);
  };

  detect_k<<<dim3(1), dim3(64), 0, stream>>>((const unsigned*)enc_ln, flag);

  // ---------------- encoder ----------------
  wtr_k<<<dim3(8, 8, 16),  dim3(256), 0, stream>>>(enc_W,   W4,  DM,  DM,   WtQ, W4,  flag);
  wtr_k<<<dim3(32, 8, 4),  dim3(256), 0, stream>>>(enc_fW1, FFW, DM,  DFF,  Wt1, FFW, flag);
  wtr_k<<<dim3(8, 32, 4),  dim3(256), 0, stream>>>(enc_fW2, FFW, DFF, DM,   Wt2, FFW, flag);
  embed_k<<<dim3(32768), dim3(256), 0, stream>>>(x, pe_s, Hh, Hl, flag);
  for (int l = 0; l < 4; l++) {
    attn_self(WtQ + (long)l * 4 * W4, enc_b, (long)l * 4 * DM);
    addln(Hh, Hl, Yf, enc_ln, ((long)l * 2 + 0) * 2 * DM, Hh, Hl);
    ffn(Wt1 + (long)l * FFW, enc_fb1, (long)l * DFF,
        Wt2 + (long)l * FFW, enc_fb2, (long)l * DM);
    addln(Hh, Hl, Yf, enc_ln, ((long)l * 2 + 1) * 2 * DM, Hh, Hl);
  }
  addln(Hh, Hl, nullptr, enc_fln, 0, Mh, Ml);  // memory

  // ---------------- decoder (weight arena overwritten, stream-ordered) ----
  wtr_k<<<dim3(8, 8, 32),  dim3(256), 0, stream>>>(dec_W,   W4,  DM,  DM,   WtQ, W4,  flag);
  wtr_k<<<dim3(32, 8, 4),  dim3(256), 0, stream>>>(dec_fW1, FFW, DM,  DFF,  Wt1, FFW, flag);
  wtr_k<<<dim3(8, 32, 4),  dim3(256), 0, stream>>>(dec_fW2, FFW, DFF, DM,   Wt2, FFW, flag);
  embed_k<<<dim3(32768), dim3(256), 0, stream>>>(tfc, pe_t, Hh, Hl, flag);
  for (int l = 0; l < 4; l++) {
    attn_self(WtQ + ((long)l * 8) * W4, dec_b, ((long)l * 8) * DM);          // self
    addln(Hh, Hl, Yf, dec_ln, ((long)l * 3 + 0) * 2 * DM, Hh, Hl);
    attn_cross(WtQ + ((long)l * 8 + 4) * W4, dec_b, ((long)l * 8 + 4) * DM); // cross
    addln(Hh, Hl, Yf, dec_ln, ((long)l * 3 + 1) * 2 * DM, Hh, Hl);
    ffn(Wt1 + (long)l * FFW, dec_fb1, (long)l * DFF,
        Wt2 + (long)l * FFW, dec_fb2, (long)l * DM);
    addln(Hh, Hl, Yf, dec_ln, ((long)l * 3 + 2) * 2 * DM, Hh, Hl);
  }
  addln(Hh, Hl, nullptr, dec_fln, 0, Hh, Hl);

  heads_k<<<dim3(MROWS / 4), dim3(256), 0, stream>>>(
      Hh, Hl, amp_W, ph_W, amp_b, ph_b, d_out, flag);
}

// Round 13
// 3412.493 us; speedup vs baseline: 1.0327x; 1.0327x over previous
//
#include <hip/hip_runtime.h>

// ---------------------------------------------------------------------------
// TRecTransformer on MI355X. Round 13: (a) mm_k 4buf->3buf (48KB LDS -> 3
// blocks/CU, lookahead 2, vmcnt(4) steady, round-9-proven schedule) for TLP
// to fill barrier stalls (round-12 A/B showed LDS conflicts weren't the
// limiter; occupancy is). (b) add_ln vectorized: adjacent-pair u32/float2
// loads+stores (G13, was scalar 2B x 4 arrays). Swizzled-coalesced staging
// kept from round 12. Everything else identical.
// ---------------------------------------------------------------------------

#define NB 4
#define NSEQ 4096
#define NH 8
#define DQ 64
#define DM 512
#define DFF 2048
#define MROWS (NB * NSEQ)          // 16384
#define SZ ((long)MROWS * DM)      // 8388608 elems

typedef unsigned short u16;
typedef unsigned int u32;
typedef __bf16 bfv8 __attribute__((ext_vector_type(8)));
typedef float f32x4 __attribute__((ext_vector_type(4)));

__device__ __forceinline__ float bf2f(u16 u) {
  union { unsigned u; float f; } v; v.u = ((unsigned)u) << 16; return v.f;
}
__device__ __forceinline__ u16 f2bf(float f) {
  union { float f; unsigned u; } v; v.f = f;
  unsigned r = v.u + 0x7FFFu + ((v.u >> 16) & 1u);
  return (u16)(r >> 16);
}
__device__ __forceinline__ float ldin(const void* p, long i, int bf) {
  return bf ? bf2f(((const u16*)p)[i]) : ((const float*)p)[i];
}
// split store for the residual stream: h+l reproduces fp32 to ~2^-18 rel.
__device__ __forceinline__ void st2(float v, u16* __restrict__ h,
                                    u16* __restrict__ l, long off) {
  u16 hh = f2bf(v);
  h[off] = hh;
  l[off] = f2bf(v - bf2f(hh));
}
__device__ __forceinline__ float ld2(const u16* __restrict__ h,
                                     const u16* __restrict__ l, long off) {
  return bf2f(h[off]) + bf2f(l[off]);
}
// async global->LDS, 16B per lane. lds base must be wave-uniform; HW writes
// lane i's 16B at base + i*16.
__device__ __forceinline__ void gld16(const u16* g, u16* l) {
  __builtin_amdgcn_global_load_lds(
      (const __attribute__((address_space(1))) unsigned int*)g,
      (__attribute__((address_space(3))) unsigned int*)l, 16, 0, 0);
}

// --- dtype probe -----------------------------------------------------------
__global__ void detect_k(const unsigned* __restrict__ lnp, int* __restrict__ flag) {
  if (threadIdx.x == 0 && blockIdx.x == 0)
    *flag = (lnp[0] == 0x3F803F80u) ? 1 : 0;
}

// --- weight transpose: W[K][N] (input dtype) -> dst[N][K] bf16, batched -----
__global__ __launch_bounds__(256) void wtr_k(
    const void* __restrict__ W, long srcstride, int K, int N,
    u16* __restrict__ dst, long dststride, const int* __restrict__ flag) {
  int bf = *flag;
  __shared__ u16 tile[64][65];
  long mb = blockIdx.z;
  int n0 = blockIdx.x * 64, k0 = blockIdx.y * 64;
  int t = threadIdx.x;
  int r = t >> 2, c0 = (t & 3) << 4;
  long sb = mb * srcstride;
#pragma unroll
  for (int c = 0; c < 16; c++)
    tile[r][c0 + c] = f2bf(ldin(W, sb + (long)(k0 + r) * N + n0 + c0 + c, bf));
  __syncthreads();
  long db = mb * dststride;
#pragma unroll
  for (int c = 0; c < 16; c++)
    dst[db + (long)(n0 + r) * K + k0 + c0 + c] = tile[c0 + c][r];
}

// --- embed: row = concat(x[b,n,0:2], pe[n,0:510]) -> split stream ----------
__global__ __launch_bounds__(256) void embed_k(
    const void* __restrict__ xin, const void* __restrict__ pe,
    u16* __restrict__ Hh, u16* __restrict__ Hl,
    const int* __restrict__ flag) {
  int bf = *flag;
  long idx = (long)blockIdx.x * 256 + threadIdx.x;   // < MROWS*DM
  long row = idx >> 9;
  int  c   = (int)(idx & 511);
  long n   = row & (NSEQ - 1);
  float v = (c < 2) ? ldin(xin, row * 2 + c, bf)
                    : ldin(pe, n * 510 + (c - 2), bf);
  st2(v, Hh, Hl, idx);
}

// --- MFMA GEMM: C[M,N] = act(A @ Bt^T + bias) ------------------------------
// A: one bf16 plane, lda stride. 3-buffer depth-2 counted-vmcnt pipeline
// (48 KB -> 3 blocks/CU). Prologue issues tiles 0,1; per step: vmcnt(4)
// [tile i landed, i+1 in flight] -> s_barrier -> sched_barrier(0) ->
// issue tile i+2 -> compute i (setprio around MFMA cluster). Last step
// peeled with vmcnt(0).
// Swizzled-coalesced staging (rule #21): slot s loads global
// (row = s>>2, kc = (s&3)^((s>>3)&3)); DMA writes slot s linearly.
// Fragment (r,kg) reads slot r*4 + (kg ^ ((r>>1)&3)).
// Out: Ch u16 via wave-private LDS-staged coalesced uint2 stores, or Cf
// fp32 direct (accum optional). act = (cc < actT) ? act0 : act1.
// Tile 128x128, BK=32, 4 waves, XCD-bijective swizzle (nwg % 8 == 0).
// Dynamic LDS: 3 bufs x 2 tensors x 4096 u16 = 48 KB.
__global__ __launch_bounds__(256) void mm_k(
    const u16* __restrict__ A, long lda,
    const u16* __restrict__ Bt, long ldb, int K,
    const void* __restrict__ bias, long boff, int hasb,
    u16* __restrict__ Ch, float* __restrict__ Cf, int accum, long ldc,
    int actT, int act0, int act1, int nbx, const int* __restrict__ flag) {
  extern __shared__ __align__(16) u16 S[];         // [3][2][4096]
  const int t = threadIdx.x;
  const int nwg = gridDim.x;
  const int cpx = nwg >> 3;
  const int swz = (blockIdx.x & 7) * cpx + (blockIdx.x >> 3);
  const long row0 = (long)(swz / nbx) * 128;
  const long col0 = (long)(swz % nbx) * 128;
  // swizzled-coalesced slot map: slot s -> row = s>>2, kc = (s&3)^((s>>3)&3)
  const int s0 = t, s1 = t + 256;
  const int r0 = s0 >> 2, kc0 = (s0 & 3) ^ ((s0 >> 3) & 3);
  const int r1 = s1 >> 2, kc1 = (s1 & 3) ^ ((s1 >> 3) & 3);
  const u16* pA0 = A + (row0 + r0) * lda + 8 * kc0;
  const u16* pA1 = A + (row0 + r1) * lda + 8 * kc1;
  const u16* pB0 = Bt + (col0 + r0) * ldb + 8 * kc0;
  const u16* pB1 = Bt + (col0 + r1) * ldb + 8 * kc1;
  const int lane = t & 63, w = t >> 6;
  // wave-uniform LDS slot bases (slot 64w and 64w+256), 8 u16/slot
  const long wb0 = (long)(w * 64) * 8;
  const long wb1 = (long)(w * 64 + 256) * 8;
  const int kg = lane >> 4, q = lane & 15;
  const int xq = (q >> 1) & 3;           // read-side swizzle key
  const int kgx = (kg ^ xq) * 8;         // swizzled k-chunk offset (u16)
  const int wm = (w >> 1) * 64, wn = (w & 1) * 64;
  f32x4 acc[4][4] = {};

  auto tbase = [&](int b, int tns) -> u16* { return S + (((b << 1) + tns) << 12); };
  auto issue = [&](int b, int k) {
    u16* bA = tbase(b, 0);
    u16* bB = tbase(b, 1);
    gld16(pA0 + k, bA + wb0); gld16(pA1 + k, bA + wb1);
    gld16(pB0 + k, bB + wb0); gld16(pB1 + k, bB + wb1);
  };
  auto compute = [&](int b) {
    const u16* sA = tbase(b, 0);
    const u16* sB = tbase(b, 1);
    bfv8 fa[4];
#pragma unroll
    for (int i = 0; i < 4; i++)
      fa[i] = *(const bfv8*)(sA + (long)(wm + i * 16 + q) * 32 + kgx);
    __builtin_amdgcn_s_setprio(1);
#pragma unroll
    for (int j = 0; j < 4; j++) {
      bfv8 fb = *(const bfv8*)(sB + (long)(wn + j * 16 + q) * 32 + kgx);
#pragma unroll
      for (int i = 0; i < 4; i++)
        acc[i][j] = __builtin_amdgcn_mfma_f32_16x16x32_bf16(fa[i], fb, acc[i][j], 0, 0, 0);
    }
    __builtin_amdgcn_s_setprio(0);
  };

  const int nt = K >> 5;                  // 16 / 64 K-steps (>= 2)
  issue(0, 0);
  issue(1, 32);
  for (int i = 0; i < nt - 1; ++i) {      // steady state: lookahead 2
    asm volatile("s_waitcnt vmcnt(4)" ::: "memory");   // tile i landed
    __builtin_amdgcn_s_barrier();
    __builtin_amdgcn_sched_barrier(0);
    if (i + 2 < nt) issue((i + 2) % 3, (i + 2) * 32);  // buf freed at barrier
    compute(i % 3);
  }
  asm volatile("s_waitcnt vmcnt(0)" ::: "memory");     // last tile landed
  __builtin_amdgcn_s_barrier();
  __builtin_amdgcn_sched_barrier(0);
  compute((nt - 1) % 3);

  __syncthreads();                       // all reads of S done; reuse as ws
  const int bf = *flag;
  if (Ch) {
    // Wave-private staged epilogue: u16 quadrant [64][stride 68], then
    // coalesced uint2 stores (each 16-lane group covers a 128B row run).
    u16* ws = S + (long)w * 4352;        // 64*68 u16 = 8704 B/wave (34816<=48K)
#pragma unroll
    for (int j = 0; j < 4; j++) {
      const long cc = col0 + wn + j * 16 + q;
      const int act = (cc < actT) ? act0 : act1;
      const float bv = hasb ? ldin(bias, boff + cc, bf) : 0.f;
#pragma unroll
      for (int i = 0; i < 4; i++)
#pragma unroll
        for (int r = 0; r < 4; r++) {
          float v = acc[i][j][r] + bv;
          if (act == 1) v = (v > 0.f) ? v + 1.f : __expf(v);
          else if (act == 2) v = fmaxf(v, 0.f);
          ws[(i * 16 + kg * 4 + r) * 68 + j * 16 + q] = f2bf(v);
        }
    }
    asm volatile("s_waitcnt lgkmcnt(0)" ::: "memory"); // wave ws writes done
    __builtin_amdgcn_sched_barrier(0);
#pragma unroll
    for (int m = 0; m < 16; m++) {
      const int slot = m * 64 + lane;
      const int row = slot >> 4, seg = slot & 15;
      uint2 c2 = *(const uint2*)&ws[row * 68 + seg * 4];
      const long off = (row0 + wm + row) * ldc + col0 + wn + seg * 4;
      *(uint2*)&Ch[off] = c2;
    }
  } else {
#pragma unroll
    for (int j = 0; j < 4; j++) {
      const long cc = col0 + wn + j * 16 + q;
      const int act = (cc < actT) ? act0 : act1;
      const float bv = hasb ? ldin(bias, boff + cc, bf) : 0.f;
#pragma unroll
      for (int i = 0; i < 4; i++) {
        const long rb = row0 + wm + i * 16 + kg * 4;
#pragma unroll
        for (int r = 0; r < 4; r++) {
          float v = acc[i][j][r] + bv;
          if (act == 1) v = (v > 0.f) ? v + 1.f : __expf(v);
          else if (act == 2) v = fmaxf(v, 0.f);
          const long off = (rb + r) * ldc + cc;
          Cf[off] = accum ? Cf[off] + v : v;
        }
      }
    }
  }
}

// --- kv partial: per (b,h,chunk): kv_part[64][64] += k_n ⊗ v_n over 512 rows
// K at S cols [512,1024), V at [1024,1536), row stride 1536, single plane.
__global__ __launch_bounds__(256) void kv_partial_k(
    const u16* __restrict__ Sh,
    float* __restrict__ kvp, float* __restrict__ ksp) {
  int bh = blockIdx.x;           // 0..31
  int b = bh >> 3, h = bh & 7;
  int nc = blockIdx.y;           // 0..7
  int tid = threadIdx.x;
  __shared__ float Ks[8][64], Vs[8][64];
  float acc[16] = {};
  float ks = 0.f;
  int d  = tid >> 2;             // 0..63
  int e0 = (tid & 3) << 4;       // 0,16,32,48
  int lr = tid >> 5;             // 0..7
  int lc = (tid & 31) << 1;      // 0..62
  long base = ((long)b * NSEQ + (long)nc * 512) * 1536 + 512 + h * DQ;
  for (int n8 = 0; n8 < 64; n8++) {
    long gg = base + (long)(n8 * 8 + lr) * 1536 + lc;
    u32 k2 = *(const u32*)(Sh + gg);
    u32 v2 = *(const u32*)(Sh + gg + 512);
    __syncthreads();
    Ks[lr][lc]     = bf2f((u16)k2);
    Ks[lr][lc + 1] = bf2f((u16)(k2 >> 16));
    Vs[lr][lc]     = bf2f((u16)v2);
    Vs[lr][lc + 1] = bf2f((u16)(v2 >> 16));
    __syncthreads();
#pragma unroll
    for (int r2 = 0; r2 < 8; r2++) {
      float kd = Ks[r2][d];
#pragma unroll
      for (int m = 0; m < 16; m++) acc[m] += kd * Vs[r2][e0 + m];
    }
    if (tid < 64) {
#pragma unroll
      for (int r2 = 0; r2 < 8; r2++) ks += Ks[r2][tid];
    }
  }
  long ob = ((long)bh * 8 + nc) * 4096 + (long)d * 64 + e0;
#pragma unroll
  for (int m = 0; m < 16; m++) kvp[ob + m] = acc[m];
  if (tid < 64) ksp[((long)bh * 8 + nc) * 64 + tid] = ks;
}

// --- kv reduce: sum the 8 chunks ------------------------------------------
__global__ __launch_bounds__(256) void kv_reduce_k(
    const float* __restrict__ kvp, const float* __restrict__ ksp,
    float* __restrict__ kv, float* __restrict__ ksum) {
  int bh = blockIdx.x;
  int tid = threadIdx.x;
  for (int i = tid; i < 4096; i += 256) {
    float s = 0.f;
#pragma unroll
    for (int c = 0; c < 8; c++) s += kvp[((long)bh * 8 + c) * 4096 + i];
    kv[(long)bh * 4096 + i] = s;
  }
  if (tid < 64) {
    float s = 0.f;
#pragma unroll
    for (int c = 0; c < 8; c++) s += ksp[((long)bh * 8 + c) * 64 + tid];
    ksum[(long)bh * 64 + tid] = s;
  }
}

// --- o = (q @ kv) / (q·ksum + eps); Q from S cols [0,512), O in place ------
__global__ __launch_bounds__(256) void attn_o_k(
    u16* __restrict__ Sh,
    const float* __restrict__ kv, const float* __restrict__ ksum) {
  int bh = blockIdx.x;
  int b = bh >> 3, h = bh & 7;
  int n0 = blockIdx.y * 64;
  int tid = threadIdx.x;
  __shared__ float Qs[64][65];
  __shared__ float KVs[64][64];
  __shared__ float ks_s[64];
  __shared__ float dinv[64];
  for (int i = tid; i < 4096; i += 256) {
    KVs[i >> 6][i & 63] = kv[(long)bh * 4096 + i];
    long qi = ((long)b * NSEQ + n0 + (i >> 6)) * 1536 + h * DQ + (i & 63);
    Qs[i >> 6][i & 63] = bf2f(Sh[qi]);
  }
  if (tid < 64) ks_s[tid] = ksum[(long)bh * 64 + tid];
  __syncthreads();
  if (tid < 64) {
    float s = 0.f;
#pragma unroll
    for (int dd = 0; dd < 64; dd++) s += Qs[tid][dd] * ks_s[dd];
    dinv[tid] = 1.f / (s + 1e-6f);
  }
  __syncthreads();
  int tx = tid & 15, ty = tid >> 4;
  float acc[4][4] = {};
#pragma unroll 4
  for (int dd = 0; dd < 64; dd++) {
    float a[4];
#pragma unroll
    for (int i = 0; i < 4; i++) a[i] = Qs[(ty << 2) + i][dd];
    float4 b4 = *(const float4*)&KVs[dd][tx << 2];
    float bb[4] = {b4.x, b4.y, b4.z, b4.w};
#pragma unroll
    for (int i = 0; i < 4; i++)
#pragma unroll
      for (int j = 0; j < 4; j++) acc[i][j] += a[i] * bb[j];
  }
#pragma unroll
  for (int i = 0; i < 4; i++) {
    float z = dinv[(ty << 2) + i];
    long ro = ((long)b * NSEQ + n0 + (ty << 2) + i) * 1536 + h * DQ + (tx << 2);
#pragma unroll
    for (int j = 0; j < 4; j++) Sh[ro + j] = f2bf(acc[i][j] * z);
  }
}

// --- Out = LN(Xh+Xl (+Yf)) * scale + bias, split stream out ----------------
// Vectorized: thread t handles adjacent elems 2t, 2t+1 (u32/float2 access).
__global__ __launch_bounds__(256) void add_ln_k(
    const u16* __restrict__ Xh, const u16* __restrict__ Xl,
    const float* __restrict__ Yf,
    const void* __restrict__ lnp, long lnoff,
    u16* __restrict__ Oh, u16* __restrict__ Ol,
    const int* __restrict__ flag) {
  int bf = *flag;
  long r = blockIdx.x;
  int tid = threadIdx.x;
  long base = r * DM;
  const int c0 = tid * 2;
  u32 xh2 = *(const u32*)(Xh + base + c0);
  u32 xl2 = *(const u32*)(Xl + base + c0);
  float x0 = bf2f((u16)xh2) + bf2f((u16)xl2);
  float x1 = bf2f((u16)(xh2 >> 16)) + bf2f((u16)(xl2 >> 16));
  if (Yf) {
    float2 y2 = *(const float2*)(Yf + base + c0);
    x0 += y2.x; x1 += y2.y;
  }
  float s = x0 + x1, sq = x0 * x0 + x1 * x1;
  for (int off = 32; off; off >>= 1) {
    s  += __shfl_down(s, off, 64);
    sq += __shfl_down(sq, off, 64);
  }
  __shared__ float red[8];
  __shared__ float mv[2];
  int w = tid >> 6;
  if ((tid & 63) == 0) { red[w] = s; red[4 + w] = sq; }
  __syncthreads();
  if (tid == 0) {
    float S = red[0] + red[1] + red[2] + red[3];
    float Q2 = red[4] + red[5] + red[6] + red[7];
    float m = S * (1.f / 512.f);
    float v = Q2 * (1.f / 512.f) - m * m;
    mv[0] = m; mv[1] = rsqrtf(v + 1e-5f);
  }
  __syncthreads();
  float m = mv[0], rs = mv[1];
  float y0 = (x0 - m) * rs * ldin(lnp, lnoff + c0, bf) + ldin(lnp, lnoff + 512 + c0, bf);
  float y1 = (x1 - m) * rs * ldin(lnp, lnoff + c0 + 1, bf) + ldin(lnp, lnoff + 512 + c0 + 1, bf);
  u16 h0 = f2bf(y0), l0 = f2bf(y0 - bf2f(h0));
  u16 h1 = f2bf(y1), l1 = f2bf(y1 - bf2f(h1));
  *(u32*)(Oh + base + c0) = (u32)h0 | ((u32)h1 << 16);
  *(u32*)(Ol + base + c0) = (u32)l0 | ((u32)l1 << 16);
}

// --- heads: out[r,0]=t·ampW+ab, out[r,1]=tanh(t·phW+pb) --------------------
__global__ __launch_bounds__(256) void heads_k(
    const u16* __restrict__ Th, const u16* __restrict__ Tl,
    const void* __restrict__ aW, const void* __restrict__ pW,
    const void* __restrict__ ab, const void* __restrict__ pb,
    void* __restrict__ out, const int* __restrict__ flag) {
  int bf = *flag;
  int tid = threadIdx.x, w = tid >> 6, ln = tid & 63;
  long r = (long)blockIdx.x * 4 + w;
  float sa = 0.f, sp = 0.f;
#pragma unroll
  for (int i = 0; i < 8; i++) {
    int d = ln + i * 64;
    float xv = ld2(Th, Tl, r * DM + d);
    sa += xv * ldin(aW, d, bf);
    sp += xv * ldin(pW, d, bf);
  }
  for (int off = 32; off; off >>= 1) {
    sa += __shfl_down(sa, off, 64);
    sp += __shfl_down(sp, off, 64);
  }
  if (ln == 0) {
    float amp = sa + ldin(ab, 0, bf);
    float ph  = tanhf(sp + ldin(pb, 0, bf));
    if (bf) {
      ((u16*)out)[r * 2]     = f2bf(amp);
      ((u16*)out)[r * 2 + 1] = f2bf(ph);
    } else {
      ((float*)out)[r * 2]     = amp;
      ((float*)out)[r * 2 + 1] = ph;
    }
  }
}

// ---------------------------------------------------------------------------
extern "C" void kernel_launch(void* const* d_in, const int* in_sizes, int n_in,
                              void* d_out, int out_size, void* d_ws, size_t ws_size,
                              hipStream_t stream) {
  const void* x       = d_in[0];
  const void* tfc     = d_in[1];
  const void* pe_s    = d_in[2];
  const void* pe_t    = d_in[3];
  const void* enc_W   = d_in[4];
  const void* enc_b   = d_in[5];
  const void* enc_ln  = d_in[6];
  const void* enc_fW1 = d_in[7];
  const void* enc_fb1 = d_in[8];
  const void* enc_fW2 = d_in[9];
  const void* enc_fb2 = d_in[10];
  const void* enc_fln = d_in[11];
  const void* dec_W   = d_in[12];
  const void* dec_b   = d_in[13];
  const void* dec_ln  = d_in[14];
  const void* dec_fW1 = d_in[15];
  const void* dec_fb1 = d_in[16];
  const void* dec_fW2 = d_in[17];
  const void* dec_fb2 = d_in[18];
  const void* dec_fln = d_in[19];
  const void* amp_W   = d_in[20];
  const void* amp_b   = d_in[21];
  const void* ph_W    = d_in[22];
  const void* ph_b    = d_in[23];

  // ws layout, u16 units (extents proven rounds 2-12):
  //   [0,2SZ)   : Hh | Hl  residual stream, split (32 MiB)
  //   [2SZ,4SZ) : Mh | Ml  memory, split (32 MiB)
  //   [4SZ,10SZ): scratch union
  //       attn: S = [16384][1536] u16 single plane at [4SZ,7SZ)
  //       ffn : Fc = [16384][2048] u16 at [4SZ,8SZ)
  //       both: Yf fp32 [8SZ,10SZ)
  //   [10SZ,12SZ): weight arena (32 MiB), enc staged then dec overwrites
  //   [12SZ,...) : fp32 smalls kv | ksum | ksp | kvp | flag (~4.8 MiB)
  u16* U  = (u16*)d_ws;
  u16* Hh = U;            u16* Hl = U + SZ;
  u16* Mh = U + 2 * SZ;   u16* Ml = U + 3 * SZ;
  u16* Sh = U + 4 * SZ;
  u16* Fch = U + 4 * SZ;
  float* Yf = (float*)(U + 8 * SZ);
  u16* WtQ = U + 10 * SZ;            // qkvo: enc 16xW4 / dec 32xW4
  u16* Wt1 = WtQ + 8388608;          // fW1^T: 4xFFW
  u16* Wt2 = WtQ + 12582912;         // fW2^T: 4xFFW
  float* F = (float*)(U + 12 * SZ);
  float* kvb   = F;                   // 32*4096
  float* ksumb = kvb + 32 * 4096;     // 2048
  float* ksp   = ksumb + 2048;        // 32*8*64
  float* kvp   = ksp + 32 * 8 * 64;   // 32*8*4096
  int*   flag  = (int*)(kvp + 32 * 8 * 4096);

  const long W4  = (long)DM * DM;    // 262144
  const long FFW = (long)DM * DFF;   // 1048576
  const size_t MMLDS = 3 * 2 * 4096 * sizeof(u16);   // 48 KB

  auto mm = [&](const u16* a, long lda, const u16* bt, long ldb, int K,
                const void* bias, long boff, int hasb,
                u16* ch, float* cf, int accum, long ldc,
                int actT, int act0, int act1, int N) {
    int nbx = N / 128;
    mm_k<<<dim3(nbx * (MROWS / 128)), dim3(256), MMLDS, stream>>>(
        a, lda, bt, ldb, K, bias, boff, hasb, ch, cf, accum, ldc,
        actT, act0, act1, nbx, flag);
  };
  auto addln = [&](const u16* xh, const u16* xl, const float* yf,
                   const void* lnp, long lnoff, u16* oh, u16* ol) {
    add_ln_k<<<dim3(MROWS), dim3(256), 0, stream>>>(
        xh, xl, yf, lnp, lnoff, oh, ol, flag);
  };
  auto attn_core = [&](const u16* Wq, const void* bb, long b0) {
    kv_partial_k<<<dim3(32, 8), dim3(256), 0, stream>>>(Sh, kvp, ksp);
    kv_reduce_k<<<dim3(32), dim3(256), 0, stream>>>(kvp, ksp, kvb, ksumb);
    attn_o_k<<<dim3(32, 64), dim3(256), 0, stream>>>(Sh, kvb, ksumb);
    // o-proj: A = O (S cols 0..511), out -> fp32 Yf (precision hedge)
    mm(Sh, 1536, Wq + 3 * W4, DM, DM, bb, b0 + 3 * DM, 1,
       nullptr, Yf, 0, DM, 512, 0, 0, DM);
  };
  auto attn_self = [&](const u16* Wq, const void* bb, long b0) {
    // fused QKV: N=1536, elu on Q,K (cc<1024), none on V
    mm(Hh, DM, Wq, DM, DM, bb, b0, 1, Sh, nullptr, 0, 1536,
       1024, 1, 0, 1536);
    attn_core(Wq, bb, b0);
  };
  auto attn_cross = [&](const u16* Wq, const void* bb, long b0) {
    mm(Hh, DM, Wq, DM, DM, bb, b0, 1, Sh, nullptr, 0, 1536,
       512, 1, 0, DM);                                              // Q
    mm(Mh, DM, Wq + W4, DM, DM, bb, b0 + DM, 1,
       Sh + 512, nullptr, 0, 1536, 512, 1, 0, 1024);                // K|V
    attn_core(Wq, bb, b0);
  };
  auto ffn = [&](const u16* w1t, const void* b1, long b1o,
                 const u16* w2t, const void* b2, long b2o) {
    // full-width: FFN1 N=2048 (relu), FFN2 K=2048 single pass -> Yf
    mm(Hh, DM, w1t, DM, DM, b1, b1o, 1, Fch, nullptr, 0, DFF, 0, 2, 2, DFF);
    mm(Fch, DFF, w2t, DFF, DFF, b2, b2o, 1, nullptr, Yf, 0, DM, 0, 0, 0, DM);
  };

  detect_k<<<dim3(1), dim3(64), 0, stream>>>((const unsigned*)enc_ln, flag);

  // ---------------- encoder ----------------
  wtr_k<<<dim3(8, 8, 16),  dim3(256), 0, stream>>>(enc_W,   W4,  DM,  DM,   WtQ, W4,  flag);
  wtr_k<<<dim3(32, 8, 4),  dim3(256), 0, stream>>>(enc_fW1, FFW, DM,  DFF,  Wt1, FFW, flag);
  wtr_k<<<dim3(8, 32, 4),  dim3(256), 0, stream>>>(enc_fW2, FFW, DFF, DM,   Wt2, FFW, flag);
  embed_k<<<dim3(32768), dim3(256), 0, stream>>>(x, pe_s, Hh, Hl, flag);
  for (int l = 0; l < 4; l++) {
    attn_self(WtQ + (long)l * 4 * W4, enc_b, (long)l * 4 * DM);
    addln(Hh, Hl, Yf, enc_ln, ((long)l * 2 + 0) * 2 * DM, Hh, Hl);
    ffn(Wt1 + (long)l * FFW, enc_fb1, (long)l * DFF,
        Wt2 + (long)l * FFW, enc_fb2, (long)l * DM);
    addln(Hh, Hl, Yf, enc_ln, ((long)l * 2 + 1) * 2 * DM, Hh, Hl);
  }
  addln(Hh, Hl, nullptr, enc_fln, 0, Mh, Ml);  // memory

  // ---------------- decoder (weight arena overwritten, stream-ordered) ----
  wtr_k<<<dim3(8, 8, 32),  dim3(256), 0, stream>>>(dec_W,   W4,  DM,  DM,   WtQ, W4,  flag);
  wtr_k<<<dim3(32, 8, 4),  dim3(256), 0, stream>>>(dec_fW1, FFW, DM,  DFF,  Wt1, FFW, flag);
  wtr_k<<<dim3(8, 32, 4),  dim3(256), 0, stream>>>(dec_fW2, FFW, DFF, DM,   Wt2, FFW, flag);
  embed_k<<<dim3(32768), dim3(256), 0, stream>>>(tfc, pe_t, Hh, Hl, flag);
  for (int l = 0; l < 4; l++) {
    attn_self(WtQ + ((long)l * 8) * W4, dec_b, ((long)l * 8) * DM);          // self
    addln(Hh, Hl, Yf, dec_ln, ((long)l * 3 + 0) * 2 * DM, Hh, Hl);
    attn_cross(WtQ + ((long)l * 8 + 4) * W4, dec_b, ((long)l * 8 + 4) * DM); // cross
    addln(Hh, Hl, Yf, dec_ln, ((long)l * 3 + 1) * 2 * DM, Hh, Hl);
    ffn(Wt1 + (long)l * FFW, dec_fb1, (long)l * DFF,
        Wt2 + (long)l * FFW, dec_fb2, (long)l * DM);
    addln(Hh, Hl, Yf, dec_ln, ((long)l * 3 + 2) * 2 * DM, Hh, Hl);
  }
  addln(Hh, Hl, nullptr, dec_fln, 0, Hh, Hl);

  heads_k<<<dim3(MROWS / 4), dim3(256), 0, stream>>>(
      Hh, Hl, amp_W, ph_W, amp_b, ph_b, d_out, flag);
}